// Round 2
// baseline (543.639 us; speedup 1.0000x reference)
//
#include <hip/hip_runtime.h>
#include <math.h>

#define D 128

__device__ __forceinline__ float reduce_add_wave64(float v) {
    #pragma unroll
    for (int m = 32; m >= 1; m >>= 1) v += __shfl_xor(v, m, 64);
    return v;
}

// ---------------------------------------------------------------------------
// K_prep: v = W_taste @ att_dst  (so a_dst = x_taste @ v + b_taste.att_dst)
// ---------------------------------------------------------------------------
__global__ void k_prep(const float* __restrict__ Wt, const float* __restrict__ bt,
                       const float* __restrict__ attd, float* __restrict__ v_c) {
    int k = threadIdx.x;  // 0..127
    float s = 0.f;
    for (int j = 0; j < D; ++j) s += Wt[k * D + j] * attd[j];
    v_c[k] = s;
    if (k == 0) {
        float c = 0.f;
        for (int j = 0; j < D; ++j) c += bt[j] * attd[j];
        v_c[D] = c;
    }
}

// ---------------------------------------------------------------------------
// K_gemm: h = x_ing @ W_ing + b_ing  [Ni,128]; a_src = h @ att_src  [Ni]
// 128x128 tile, 256 threads, 8x8 per-thread register blocking.
// sW 64KB + sX 64KB = 128KB LDS -> 1 block/CU. sX is XOR-swizzled on the
// 16B-block index with (row>>3)&7 so the 4 row-groups of a wave read 4
// distinct bank groups (conflict-free ds_read_b128).
// ---------------------------------------------------------------------------
__global__ __launch_bounds__(256, 1)
void k_gemm_hi(const float* __restrict__ x, const float* __restrict__ W,
               const float* __restrict__ b, const float* __restrict__ att,
               float* __restrict__ h, float* __restrict__ a_src, int Ni) {
    __shared__ float sW[D * D];   // 64 KB, row-major W[k][c]
    __shared__ float sX[D * D];   // 64 KB, swizzled x tile
    const int tid  = threadIdx.x;
    const int row0 = blockIdx.x * 128;

    #pragma unroll
    for (int j = 0; j < 16; ++j) {
        int idx = (j * 256 + tid) * 4;
        *(float4*)&sW[idx] = *(const float4*)&W[idx];
    }
    #pragma unroll
    for (int j = 0; j < 16; ++j) {
        int idx = (j * 256 + tid) * 4;   // flat float index into 128x128
        int r   = idx >> 7;
        int c   = idx & 127;
        int kbs = ((c >> 2) ^ ((r >> 3) & 7)) << 2;  // swizzled 16B block
        float4 v = {0.f, 0.f, 0.f, 0.f};
        if (row0 + r < Ni) v = *(const float4*)&x[(long)(row0 + r) * D + c];
        *(float4*)&sX[r * D + kbs] = v;
    }
    __syncthreads();

    const int tx = tid & 15;   // cols tx*8 .. tx*8+7
    const int ty = tid >> 4;   // rows ty*8 .. ty*8+7   (row>>3 == ty)
    float acc[8][8] = {};
    const int xsw = ty & 7;

    #pragma unroll 2
    for (int k = 0; k < D; k += 4) {
        const int kbs = (((k >> 2) ^ xsw) << 2);
        float4 xr[8];
        #pragma unroll
        for (int r = 0; r < 8; ++r)
            xr[r] = *(float4*)&sX[(ty * 8 + r) * D + kbs];
        float4 w0[4], w1[4];
        #pragma unroll
        for (int kk = 0; kk < 4; ++kk) {
            w0[kk] = *(float4*)&sW[(k + kk) * D + tx * 8];
            w1[kk] = *(float4*)&sW[(k + kk) * D + tx * 8 + 4];
        }
        #pragma unroll
        for (int r = 0; r < 8; ++r) {
            const float4 xv = xr[r];
            #pragma unroll
            for (int kk = 0; kk < 4; ++kk) {
                const float xk = (kk == 0) ? xv.x : (kk == 1) ? xv.y
                               : (kk == 2) ? xv.z : xv.w;
                acc[r][0] += xk * w0[kk].x;
                acc[r][1] += xk * w0[kk].y;
                acc[r][2] += xk * w0[kk].z;
                acc[r][3] += xk * w0[kk].w;
                acc[r][4] += xk * w1[kk].x;
                acc[r][5] += xk * w1[kk].y;
                acc[r][6] += xk * w1[kk].z;
                acc[r][7] += xk * w1[kk].w;
            }
        }
    }

    const float4 bb0 = *(const float4*)&b[tx * 8];
    const float4 bb1 = *(const float4*)&b[tx * 8 + 4];
    const float4 aa0 = *(const float4*)&att[tx * 8];
    const float4 aa1 = *(const float4*)&att[tx * 8 + 4];
    #pragma unroll
    for (int r = 0; r < 8; ++r) {
        int row = row0 + ty * 8 + r;
        if (row < Ni) {
            float4 h0, h1;
            h0.x = acc[r][0] + bb0.x;  h0.y = acc[r][1] + bb0.y;
            h0.z = acc[r][2] + bb0.z;  h0.w = acc[r][3] + bb0.w;
            h1.x = acc[r][4] + bb1.x;  h1.y = acc[r][5] + bb1.y;
            h1.z = acc[r][6] + bb1.z;  h1.w = acc[r][7] + bb1.w;
            *(float4*)&h[(long)row * D + tx * 8]     = h0;
            *(float4*)&h[(long)row * D + tx * 8 + 4] = h1;
            float p = h0.x * aa0.x + h0.y * aa0.y + h0.z * aa0.z + h0.w * aa0.w
                    + h1.x * aa1.x + h1.y * aa1.y + h1.z * aa1.z + h1.w * aa1.w;
            p += __shfl_xor(p, 1, 64);
            p += __shfl_xor(p, 2, 64);
            p += __shfl_xor(p, 4, 64);
            p += __shfl_xor(p, 8, 64);
            if (tx == 0) a_src[row] = p;
        }
    }
}

// ---------------------------------------------------------------------------
// K_adst: a_dst[t] = x_taste[t] . v + c     (one wave per row)
// ---------------------------------------------------------------------------
__global__ __launch_bounds__(256)
void k_adst(const float* __restrict__ xt, const float* __restrict__ v_c,
            float* __restrict__ a_dst, int Nt) {
    int wid  = (blockIdx.x * 256 + threadIdx.x) >> 6;
    int lane = threadIdx.x & 63;
    if (wid >= Nt) return;
    float2 xv = *(const float2*)&xt[(long)wid * D + lane * 2];
    float2 vv = *(const float2*)&v_c[lane * 2];
    float p = xv.x * vv.x + xv.y * vv.y;
    p = reduce_add_wave64(p);
    if (lane == 0) a_dst[wid] = p + v_c[D];
}

// ---------------------------------------------------------------------------
// Counting sort: histogram -> 1-block scan -> scatter (pre-gathers a_src)
// ---------------------------------------------------------------------------
__global__ void k_hist(const int* __restrict__ dst, int* __restrict__ hist, int E) {
    int i = blockIdx.x * 256 + threadIdx.x;
    if (i < E) atomicAdd(&hist[dst[i]], 1);
}

__global__ __launch_bounds__(1024)
void k_scan(const int* __restrict__ hist, int* __restrict__ offs,
            int* __restrict__ cur, int n) {
    __shared__ int sh[1024];
    int tid = threadIdx.x;
    int chunk = (n + 1023) / 1024;
    int start = tid * chunk;
    int end   = min(start + chunk, n);
    int sum = 0;
    for (int i = start; i < end; ++i) sum += hist[i];
    sh[tid] = sum;
    __syncthreads();
    for (int o = 1; o < 1024; o <<= 1) {
        int v = (tid >= o) ? sh[tid - o] : 0;
        __syncthreads();
        sh[tid] += v;
        __syncthreads();
    }
    int run = sh[tid] - sum;  // exclusive prefix
    for (int i = start; i < end; ++i) {
        offs[i] = run; cur[i] = run; run += hist[i];
    }
    if (tid == 1023) offs[n] = run;
}

__global__ void k_scatter(const int* __restrict__ src, const int* __restrict__ dst,
                          const float* __restrict__ a_src, int* __restrict__ cur,
                          int* __restrict__ s_src, float* __restrict__ s_asrc, int E) {
    int i = blockIdx.x * 256 + threadIdx.x;
    if (i >= E) return;
    int d = dst[i], s = src[i];
    int pos = atomicAdd(&cur[d], 1);
    s_src[pos]  = s;
    s_asrc[pos] = a_src[s];
}

// ---------------------------------------------------------------------------
// K_agg: one wave per taste node: softmax over its edges (max-subtract is
// unnecessary: alpha ~ N(0,2), |alpha| <~ 10) + weighted gather-sum of h
// rows; ReLU + residual.
// ---------------------------------------------------------------------------
__global__ __launch_bounds__(256)
void k_agg(const int* __restrict__ offs, const int* __restrict__ s_src,
           const float* __restrict__ s_asrc, const float* __restrict__ a_dst,
           const float* __restrict__ h, const float* __restrict__ xt,
           float* __restrict__ outT, int Nt) {
    int t    = blockIdx.x * 4 + (threadIdx.x >> 6);
    int lane = threadIdx.x & 63;
    if (t >= Nt) return;
    int s0 = offs[t], s1 = offs[t + 1];
    float ad = a_dst[t];

    float z = 0.f;
    for (int i = s0 + lane; i < s1; i += 64) {
        float al = s_asrc[i] + ad;
        al = al > 0.f ? al : 0.2f * al;
        z += __expf(al);
    }
    z = reduce_add_wave64(z);
    float zinv = 1.0f / (z + 1e-16f);

    float2 acc = {0.f, 0.f};
    for (int i = s0; i < s1; ++i) {          // uniform loop; lanes = columns
        int s = s_src[i];
        float al = s_asrc[i] + ad;
        al = al > 0.f ? al : 0.2f * al;
        float w = __expf(al) * zinv;
        float2 hv = *(const float2*)&h[(long)s * D + lane * 2];
        acc.x += hv.x * w;
        acc.y += hv.y * w;
    }
    float2 xv = *(const float2*)&xt[(long)t * D + lane * 2];
    float2 o;
    o.x = fmaxf(acc.x, 0.f) + xv.x;
    o.y = fmaxf(acc.y, 0.f) + xv.y;
    *(float2*)&outT[(long)t * D + lane * 2] = o;
}

// ---------------------------------------------------------------------------
// BatchNorm: column sums/sumsq (grid-partial + atomics), then normalize+ReLU
// ---------------------------------------------------------------------------
__global__ __launch_bounds__(256)
void k_bnstats(const float* __restrict__ outT, float* __restrict__ csum,
               float* __restrict__ csq, int Nt) {
    int c    = threadIdx.x & 127;
    int half = threadIdx.x >> 7;
    float s = 0.f, q = 0.f;
    for (int r = blockIdx.x * 2 + half; r < Nt; r += gridDim.x * 2) {
        float v = outT[(long)r * D + c];
        s += v; q += v * v;
    }
    atomicAdd(&csum[c], s);
    atomicAdd(&csq[c], q);
}

__global__ __launch_bounds__(256)
void k_bnapply(float* __restrict__ outT, const float* __restrict__ csum,
               const float* __restrict__ csq, const float* __restrict__ gamma,
               const float* __restrict__ beta, int Nt) {
    int i4 = blockIdx.x * 256 + threadIdx.x;
    int total = Nt * (D / 4);
    if (i4 >= total) return;
    int c = (i4 * 4) & 127;
    float invN = 1.0f / (float)Nt;
    float4 v = *(float4*)&outT[(long)i4 * 4];
    float4 o;
    {
        float m0 = csum[c + 0] * invN, m1 = csum[c + 1] * invN;
        float m2 = csum[c + 2] * invN, m3 = csum[c + 3] * invN;
        float r0 = rsqrtf(csq[c + 0] * invN - m0 * m0 + 1e-5f);
        float r1 = rsqrtf(csq[c + 1] * invN - m1 * m1 + 1e-5f);
        float r2 = rsqrtf(csq[c + 2] * invN - m2 * m2 + 1e-5f);
        float r3 = rsqrtf(csq[c + 3] * invN - m3 * m3 + 1e-5f);
        o.x = fmaxf(gamma[c + 0] * (v.x - m0) * r0 + beta[c + 0], 0.f);
        o.y = fmaxf(gamma[c + 1] * (v.y - m1) * r1 + beta[c + 1], 0.f);
        o.z = fmaxf(gamma[c + 2] * (v.z - m2) * r2 + beta[c + 2], 0.f);
        o.w = fmaxf(gamma[c + 3] * (v.w - m3) * r3 + beta[c + 3], 0.f);
    }
    *(float4*)&outT[(long)i4 * 4] = o;
}

// ---------------------------------------------------------------------------
extern "C" void kernel_launch(void* const* d_in, const int* in_sizes, int n_in,
                              void* d_out, int out_size, void* d_ws, size_t ws_size,
                              hipStream_t stream) {
    const float* x_ing   = (const float*)d_in[0];
    const float* x_taste = (const float*)d_in[1];
    const float* W_ing   = (const float*)d_in[2];
    const float* b_ing   = (const float*)d_in[3];
    const float* W_taste = (const float*)d_in[4];
    const float* b_taste = (const float*)d_in[5];
    const float* att_src = (const float*)d_in[6];
    const float* att_dst = (const float*)d_in[7];
    const float* gamma   = (const float*)d_in[8];
    const float* beta    = (const float*)d_in[9];
    const int*   e_src   = (const int*)d_in[10];
    const int*   e_dst   = (const int*)d_in[11];

    const int Ni = in_sizes[0] / D;
    const int Nt = in_sizes[1] / D;
    const int E  = in_sizes[10];

    // h lives in d_out's ingredient region (exactly Ni*D floats); the
    // x_ing passthrough memcpy happens AFTER k_agg has consumed h.
    float* h    = (float*)d_out;
    float* outT = (float*)d_out + (size_t)Ni * D;

    // workspace carve (each region rounded to 64 floats = 256B); ~5.2 MB total
    float* ws = (float*)d_ws;
    size_t off = 0;
    auto alloc = [&](size_t n) {
        float* p = ws + off;
        off += (n + 63) & ~(size_t)63;
        return p;
    };
    float* asrc   = alloc(Ni);
    float* adst   = alloc(Nt);
    float* v_c    = alloc(D + 64);
    int*   hist   = (int*)alloc(Nt);         // zeroed (contiguous with csum/csq)
    float* csum   = alloc(D);                // zeroed
    float* csq    = alloc(D);                // zeroed
    int*   offs   = (int*)alloc(Nt + 1);
    int*   cur    = (int*)alloc(Nt);
    int*   s_src  = (int*)alloc(E);
    float* s_asrc = alloc(E);
    (void)off; (void)ws_size; (void)n_in; (void)out_size;

    // zero hist + csum + csq in one shot (contiguous in ws)
    size_t histR = ((size_t)Nt + 63) & ~(size_t)63;
    hipMemsetAsync(hist, 0, (histR + 256) * sizeof(float), stream);

    k_prep<<<1, 128, 0, stream>>>(W_taste, b_taste, att_dst, v_c);
    k_gemm_hi<<<(Ni + 127) / 128, 256, 0, stream>>>(x_ing, W_ing, b_ing,
                                                    att_src, h, asrc, Ni);
    k_adst<<<(Nt + 3) / 4, 256, 0, stream>>>(x_taste, v_c, adst, Nt);
    k_hist<<<(E + 255) / 256, 256, 0, stream>>>(e_dst, hist, E);
    k_scan<<<1, 1024, 0, stream>>>(hist, offs, cur, Nt);
    k_scatter<<<(E + 255) / 256, 256, 0, stream>>>(e_src, e_dst, asrc, cur,
                                                   s_src, s_asrc, E);
    k_agg<<<(Nt + 3) / 4, 256, 0, stream>>>(offs, s_src, s_asrc, adst, h,
                                            x_taste, outT, Nt);

    // ingredient output = input passthrough (after h is consumed)
    hipMemcpyAsync(d_out, x_ing, (size_t)Ni * D * sizeof(float),
                   hipMemcpyDeviceToDevice, stream);

    k_bnstats<<<256, 256, 0, stream>>>(outT, csum, csq, Nt);
    k_bnapply<<<(Nt * (D / 4) + 255) / 256, 256, 0, stream>>>(outT, csum, csq,
                                                              gamma, beta, Nt);
}

// Round 5
// 526.612 us; speedup vs baseline: 1.0323x; 1.0323x over previous
//
#include <hip/hip_runtime.h>
#include <math.h>

#define D 128

__device__ __forceinline__ float reduce_add_wave64(float v) {
    #pragma unroll
    for (int m = 32; m >= 1; m >>= 1) v += __shfl_xor(v, m, 64);
    return v;
}

// ---------------------------------------------------------------------------
// K_prep: v = W_taste @ att_dst  (so a_dst = x_taste @ v + b_taste.att_dst)
// ---------------------------------------------------------------------------
__global__ void k_prep(const float* __restrict__ Wt, const float* __restrict__ bt,
                       const float* __restrict__ attd, float* __restrict__ v_c) {
    int k = threadIdx.x;  // 0..127
    float s = 0.f;
    for (int j = 0; j < D; ++j) s += Wt[k * D + j] * attd[j];
    v_c[k] = s;
    if (k == 0) {
        float c = 0.f;
        for (int j = 0; j < D; ++j) c += bt[j] * attd[j];
        v_c[D] = c;
    }
}

// ---------------------------------------------------------------------------
// K_gemm: h = x_ing @ W_ing + b_ing  [Ni,128]; a_src = h @ att_src  [Ni]
// LDS-FREE: W (64KB) is L1/L2-resident; threads with the same tx across the
// 4 ty-groups of a wave request identical 32B W segments (coalescer merges);
// x rows are 16-lane broadcast reads. No barriers -> compiler pipelines
// loads across k-iterations. 4x8 register tile (acc=32 VGPR, ~96 total) so
// the 128-VGPR cap from __launch_bounds__(256,4) is met WITHOUT spills ->
// 16 waves/CU (4/SIMD) vs round-2's 4 waves/CU.
// ---------------------------------------------------------------------------
__global__ __launch_bounds__(256, 4)
void k_gemm_hi(const float* __restrict__ x, const float* __restrict__ W,
               const float* __restrict__ b, const float* __restrict__ att,
               float* __restrict__ h, float* __restrict__ a_src, int Ni) {
    const int tid = threadIdx.x;
    const int tx  = tid & 15;          // cols tx*8 .. tx*8+7
    const int ty  = tid >> 4;          // 0..15, rows row0 .. row0+3
    const long row0 = (long)blockIdx.x * 64 + (long)ty * 4;

    // clamped row base pointers (tail rows read row Ni-1; store is guarded)
    const float* xr[4];
    #pragma unroll
    for (int r = 0; r < 4; ++r) {
        long rr = row0 + r;
        if (rr > (long)Ni - 1) rr = (long)Ni - 1;
        xr[r] = x + rr * D;
    }
    const float* wp0 = W + tx * 8;
    const float* wp1 = W + tx * 8 + 4;

    float acc[4][8] = {};

    #pragma unroll 1
    for (int k = 0; k < D; k += 4) {
        float4 w0[4], w1[4];
        #pragma unroll
        for (int kk = 0; kk < 4; ++kk) {
            w0[kk] = *(const float4*)&wp0[(k + kk) * D];
            w1[kk] = *(const float4*)&wp1[(k + kk) * D];
        }
        #pragma unroll
        for (int r = 0; r < 4; ++r) {
            const float4 xv = *(const float4*)&xr[r][k];
            #pragma unroll
            for (int kk = 0; kk < 4; ++kk) {
                const float xk = (kk == 0) ? xv.x : (kk == 1) ? xv.y
                               : (kk == 2) ? xv.z : xv.w;
                acc[r][0] += xk * w0[kk].x;
                acc[r][1] += xk * w0[kk].y;
                acc[r][2] += xk * w0[kk].z;
                acc[r][3] += xk * w0[kk].w;
                acc[r][4] += xk * w1[kk].x;
                acc[r][5] += xk * w1[kk].y;
                acc[r][6] += xk * w1[kk].z;
                acc[r][7] += xk * w1[kk].w;
            }
        }
    }

    const float4 bb0 = *(const float4*)&b[tx * 8];
    const float4 bb1 = *(const float4*)&b[tx * 8 + 4];
    const float4 aa0 = *(const float4*)&att[tx * 8];
    const float4 aa1 = *(const float4*)&att[tx * 8 + 4];
    #pragma unroll
    for (int r = 0; r < 4; ++r) {
        long row = row0 + r;
        if (row < Ni) {
            float4 h0, h1;
            h0.x = acc[r][0] + bb0.x;  h0.y = acc[r][1] + bb0.y;
            h0.z = acc[r][2] + bb0.z;  h0.w = acc[r][3] + bb0.w;
            h1.x = acc[r][4] + bb1.x;  h1.y = acc[r][5] + bb1.y;
            h1.z = acc[r][6] + bb1.z;  h1.w = acc[r][7] + bb1.w;
            *(float4*)&h[row * D + tx * 8]     = h0;
            *(float4*)&h[row * D + tx * 8 + 4] = h1;
            float p = h0.x * aa0.x + h0.y * aa0.y + h0.z * aa0.z + h0.w * aa0.w
                    + h1.x * aa1.x + h1.y * aa1.y + h1.z * aa1.z + h1.w * aa1.w;
            p += __shfl_xor(p, 1, 64);
            p += __shfl_xor(p, 2, 64);
            p += __shfl_xor(p, 4, 64);
            p += __shfl_xor(p, 8, 64);
            if (tx == 0) a_src[row] = p;
        }
    }
}

// ---------------------------------------------------------------------------
// K_adst: a_dst[t] = x_taste[t] . v + c     (one wave per row)
// ---------------------------------------------------------------------------
__global__ __launch_bounds__(256)
void k_adst(const float* __restrict__ xt, const float* __restrict__ v_c,
            float* __restrict__ a_dst, int Nt) {
    int wid  = (blockIdx.x * 256 + threadIdx.x) >> 6;
    int lane = threadIdx.x & 63;
    if (wid >= Nt) return;
    float2 xv = *(const float2*)&xt[(long)wid * D + lane * 2];
    float2 vv = *(const float2*)&v_c[lane * 2];
    float p = xv.x * vv.x + xv.y * vv.y;
    p = reduce_add_wave64(p);
    if (lane == 0) a_dst[wid] = p + v_c[D];
}

// ---------------------------------------------------------------------------
// Counting sort: histogram -> 1-block scan -> scatter (packs src + a_src[src]
// into one int2 so the random write is a single 8B store)
// ---------------------------------------------------------------------------
__global__ void k_hist(const int* __restrict__ dst, int* __restrict__ hist, int E) {
    int i = blockIdx.x * 256 + threadIdx.x;
    if (i < E) atomicAdd(&hist[dst[i]], 1);
}

__global__ __launch_bounds__(1024)
void k_scan(const int* __restrict__ hist, int* __restrict__ offs,
            int* __restrict__ cur, int n) {
    __shared__ int sh[1024];
    int tid = threadIdx.x;
    int chunk = (n + 1023) / 1024;
    int start = tid * chunk;
    int end   = min(start + chunk, n);
    int sum = 0;
    for (int i = start; i < end; ++i) sum += hist[i];
    sh[tid] = sum;
    __syncthreads();
    for (int o = 1; o < 1024; o <<= 1) {
        int v = (tid >= o) ? sh[tid - o] : 0;
        __syncthreads();
        sh[tid] += v;
        __syncthreads();
    }
    int run = sh[tid] - sum;  // exclusive prefix
    for (int i = start; i < end; ++i) {
        offs[i] = run; cur[i] = run; run += hist[i];
    }
    if (tid == 1023) offs[n] = run;
}

__global__ void k_scatter(const int* __restrict__ src, const int* __restrict__ dst,
                          const float* __restrict__ a_src, int* __restrict__ cur,
                          int2* __restrict__ s_pack, int E) {
    int i = blockIdx.x * 256 + threadIdx.x;
    if (i >= E) return;
    int d = dst[i], s = src[i];
    int pos = atomicAdd(&cur[d], 1);
    s_pack[pos] = make_int2(s, __float_as_int(a_src[s]));
}

// ---------------------------------------------------------------------------
// K_agg: one wave per taste node. Edge metadata is preloaded LANE-PARALLEL
// (one coalesced int2 load covers up to 64 edges), exp() computed per lane,
// then the gather loop broadcasts (s,w) via shfl and accumulates with 2-way
// unroll / split accumulators for memory-level parallelism. 1/z applied once
// at the end (softmax max-subtract unnecessary: |alpha| <~ 10).
// ---------------------------------------------------------------------------
__global__ __launch_bounds__(256)
void k_agg(const int* __restrict__ offs, const int2* __restrict__ s_pack,
           const float* __restrict__ a_dst, const float* __restrict__ h,
           const float* __restrict__ xt, float* __restrict__ outT, int Nt) {
    int t    = blockIdx.x * 4 + (threadIdx.x >> 6);
    int lane = threadIdx.x & 63;
    if (t >= Nt) return;
    int s0 = offs[t], s1 = offs[t + 1];
    int deg = s1 - s0;
    float ad = a_dst[t];

    // lane-parallel preload of first 64 edges
    int   my_s = 0;
    float my_e = 0.f;
    if (lane < deg) {
        int2 sp = s_pack[s0 + lane];
        my_s = sp.x;
        float al = __int_as_float(sp.y) + ad;
        al = al > 0.f ? al : 0.2f * al;
        my_e = __expf(al);
    }
    float z = my_e;
    for (int i = s0 + 64 + lane; i < s1; i += 64) {   // rare (deg > 64)
        int2 sp = s_pack[i];
        float al = __int_as_float(sp.y) + ad;
        al = al > 0.f ? al : 0.2f * al;
        z += __expf(al);
    }
    z = reduce_add_wave64(z);
    float zinv = 1.0f / (z + 1e-16f);

    float2 acc0 = {0.f, 0.f}, acc1 = {0.f, 0.f};
    int n = deg < 64 ? deg : 64;
    int i = 0;
    for (; i + 1 < n; i += 2) {
        int   sA = __shfl(my_s, i, 64);
        float wA = __shfl(my_e, i, 64);
        int   sB = __shfl(my_s, i + 1, 64);
        float wB = __shfl(my_e, i + 1, 64);
        float2 hA = *(const float2*)&h[(long)sA * D + lane * 2];
        float2 hB = *(const float2*)&h[(long)sB * D + lane * 2];
        acc0.x += hA.x * wA;  acc0.y += hA.y * wA;
        acc1.x += hB.x * wB;  acc1.y += hB.y * wB;
    }
    if (i < n) {
        int   sA = __shfl(my_s, i, 64);
        float wA = __shfl(my_e, i, 64);
        float2 hA = *(const float2*)&h[(long)sA * D + lane * 2];
        acc0.x += hA.x * wA;  acc0.y += hA.y * wA;
    }
    for (int j = s0 + 64; j < s1; ++j) {              // rare (deg > 64)
        int2 sp = s_pack[j];
        float al = __int_as_float(sp.y) + ad;
        al = al > 0.f ? al : 0.2f * al;
        float w = __expf(al);
        float2 hv = *(const float2*)&h[(long)sp.x * D + lane * 2];
        acc0.x += hv.x * w;  acc0.y += hv.y * w;
    }

    float2 xv = *(const float2*)&xt[(long)t * D + lane * 2];
    float2 o;
    o.x = fmaxf((acc0.x + acc1.x) * zinv, 0.f) + xv.x;
    o.y = fmaxf((acc0.y + acc1.y) * zinv, 0.f) + xv.y;
    *(float2*)&outT[(long)t * D + lane * 2] = o;
}

// ---------------------------------------------------------------------------
// K_copy: x_ing -> d_out ingredient region (grid-stride float4; replaces
// hipMemcpyAsync so the copy is (a) guaranteed on the 6.3 TB/s kernel path,
// not SDMA, and (b) visible in the per-dispatch profile)
// ---------------------------------------------------------------------------
__global__ __launch_bounds__(256)
void k_copy(const float4* __restrict__ src, float4* __restrict__ dst, long n4) {
    long stride = (long)gridDim.x * 256;
    for (long i = (long)blockIdx.x * 256 + threadIdx.x; i < n4; i += stride)
        dst[i] = src[i];
}

// ---------------------------------------------------------------------------
// BatchNorm: column sums/sumsq (grid-partial + atomics), then normalize+ReLU
// ---------------------------------------------------------------------------
__global__ __launch_bounds__(256)
void k_bnstats(const float* __restrict__ outT, float* __restrict__ csum,
               float* __restrict__ csq, int Nt) {
    int c    = threadIdx.x & 127;
    int half = threadIdx.x >> 7;
    float s = 0.f, q = 0.f;
    for (int r = blockIdx.x * 2 + half; r < Nt; r += gridDim.x * 2) {
        float v = outT[(long)r * D + c];
        s += v; q += v * v;
    }
    atomicAdd(&csum[c], s);
    atomicAdd(&csq[c], q);
}

__global__ __launch_bounds__(256)
void k_bnapply(float* __restrict__ outT, const float* __restrict__ csum,
               const float* __restrict__ csq, const float* __restrict__ gamma,
               const float* __restrict__ beta, int Nt) {
    int i4 = blockIdx.x * 256 + threadIdx.x;
    int total = Nt * (D / 4);
    if (i4 >= total) return;
    int c = (i4 * 4) & 127;
    float invN = 1.0f / (float)Nt;
    float4 v = *(float4*)&outT[(long)i4 * 4];
    float4 o;
    {
        float m0 = csum[c + 0] * invN, m1 = csum[c + 1] * invN;
        float m2 = csum[c + 2] * invN, m3 = csum[c + 3] * invN;
        float r0 = rsqrtf(csq[c + 0] * invN - m0 * m0 + 1e-5f);
        float r1 = rsqrtf(csq[c + 1] * invN - m1 * m1 + 1e-5f);
        float r2 = rsqrtf(csq[c + 2] * invN - m2 * m2 + 1e-5f);
        float r3 = rsqrtf(csq[c + 3] * invN - m3 * m3 + 1e-5f);
        o.x = fmaxf(gamma[c + 0] * (v.x - m0) * r0 + beta[c + 0], 0.f);
        o.y = fmaxf(gamma[c + 1] * (v.y - m1) * r1 + beta[c + 1], 0.f);
        o.z = fmaxf(gamma[c + 2] * (v.z - m2) * r2 + beta[c + 2], 0.f);
        o.w = fmaxf(gamma[c + 3] * (v.w - m3) * r3 + beta[c + 3], 0.f);
    }
    *(float4*)&outT[(long)i4 * 4] = o;
}

// ---------------------------------------------------------------------------
extern "C" void kernel_launch(void* const* d_in, const int* in_sizes, int n_in,
                              void* d_out, int out_size, void* d_ws, size_t ws_size,
                              hipStream_t stream) {
    const float* x_ing   = (const float*)d_in[0];
    const float* x_taste = (const float*)d_in[1];
    const float* W_ing   = (const float*)d_in[2];
    const float* b_ing   = (const float*)d_in[3];
    const float* W_taste = (const float*)d_in[4];
    const float* b_taste = (const float*)d_in[5];
    const float* att_src = (const float*)d_in[6];
    const float* att_dst = (const float*)d_in[7];
    const float* gamma   = (const float*)d_in[8];
    const float* beta    = (const float*)d_in[9];
    const int*   e_src   = (const int*)d_in[10];
    const int*   e_dst   = (const int*)d_in[11];

    const int Ni = in_sizes[0] / D;
    const int Nt = in_sizes[1] / D;
    const int E  = in_sizes[10];

    // h lives in d_out's ingredient region (exactly Ni*D floats); the
    // x_ing passthrough copy happens AFTER k_agg has consumed h.
    float* h    = (float*)d_out;
    float* outT = (float*)d_out + (size_t)Ni * D;

    // workspace carve (each region rounded to 64 floats = 256B); ~7 MB total
    float* ws = (float*)d_ws;
    size_t off = 0;
    auto alloc = [&](size_t n) {
        float* p = ws + off;
        off += (n + 63) & ~(size_t)63;
        return p;
    };
    float* asrc   = alloc(Ni);
    float* adst   = alloc(Nt);
    float* v_c    = alloc(D + 64);
    int*   hist   = (int*)alloc(Nt);         // zeroed (contiguous with csum/csq)
    float* csum   = alloc(D);                // zeroed
    float* csq    = alloc(D);                // zeroed
    int*   offs   = (int*)alloc(Nt + 1);
    int*   cur    = (int*)alloc(Nt);
    int2*  s_pack = (int2*)alloc((size_t)E * 2);
    (void)off; (void)ws_size; (void)n_in; (void)out_size;

    // zero hist + csum + csq in one shot (contiguous in ws)
    size_t histR = ((size_t)Nt + 63) & ~(size_t)63;
    hipMemsetAsync(hist, 0, (histR + 256) * sizeof(float), stream);

    k_prep<<<1, 128, 0, stream>>>(W_taste, b_taste, att_dst, v_c);
    k_gemm_hi<<<(Ni + 63) / 64, 256, 0, stream>>>(x_ing, W_ing, b_ing,
                                                  att_src, h, asrc, Ni);
    k_adst<<<(Nt + 3) / 4, 256, 0, stream>>>(x_taste, v_c, adst, Nt);
    k_hist<<<(E + 255) / 256, 256, 0, stream>>>(e_dst, hist, E);
    k_scan<<<1, 1024, 0, stream>>>(hist, offs, cur, Nt);
    k_scatter<<<(E + 255) / 256, 256, 0, stream>>>(e_src, e_dst, asrc, cur,
                                                   s_pack, E);
    k_agg<<<(Nt + 3) / 4, 256, 0, stream>>>(offs, s_pack, adst, h,
                                            x_taste, outT, Nt);

    // ingredient output = input passthrough (after h is consumed)
    long n4 = (long)Ni * D / 4;
    k_copy<<<2048, 256, 0, stream>>>((const float4*)x_ing, (float4*)d_out, n4);

    k_bnstats<<<256, 256, 0, stream>>>(outT, csum, csq, Nt);
    k_bnapply<<<(Nt * (D / 4) + 255) / 256, 256, 0, stream>>>(outT, csum, csq,
                                                              gamma, beta, Nt);
}

// Round 6
// 507.000 us; speedup vs baseline: 1.0723x; 1.0387x over previous
//
#include <hip/hip_runtime.h>
#include <math.h>

#define D 128

__device__ __forceinline__ float reduce_add_wave64(float v) {
    #pragma unroll
    for (int m = 32; m >= 1; m >>= 1) v += __shfl_xor(v, m, 64);
    return v;
}

// ---------------------------------------------------------------------------
// K_prep: v = W_taste @ att_dst  (so a_dst = x_taste @ v + b_taste.att_dst)
// ---------------------------------------------------------------------------
__global__ void k_prep(const float* __restrict__ Wt, const float* __restrict__ bt,
                       const float* __restrict__ attd, float* __restrict__ v_c) {
    int k = threadIdx.x;  // 0..127
    float s = 0.f;
    for (int j = 0; j < D; ++j) s += Wt[k * D + j] * attd[j];
    v_c[k] = s;
    if (k == 0) {
        float c = 0.f;
        for (int j = 0; j < D; ++j) c += bt[j] * attd[j];
        v_c[D] = c;
    }
}

// ---------------------------------------------------------------------------
// K_gemm: h = x_ing @ W_ing + b_ing  [Ni,128]; a_src = h @ att_src  [Ni]
// LDS-free, REGISTER DOUBLE-BUFFERED. Round-5 showed the compiler compresses
// a single-buffer loop to 40 VGPRs by serializing load->wait->FMA (VALUBusy
// 22%). Two explicitly-named register sets (wA/xA, wB/xB) force ~145 live
// VGPRs and give every load a full 128-FMA phase of latency cover. Loads for
// the NEXT set are issued before the FMA block of the CURRENT set, so the
// compiler emits counted vmcnt waits instead of vmcnt(0) stalls.
// ---------------------------------------------------------------------------
__global__ __launch_bounds__(256, 2)
void k_gemm_hi(const float* __restrict__ x, const float* __restrict__ W,
               const float* __restrict__ b, const float* __restrict__ att,
               float* __restrict__ h, float* __restrict__ a_src, int Ni) {
    const int tid = threadIdx.x;
    const int tx  = tid & 15;          // cols tx*8 .. tx*8+7
    const int ty  = tid >> 4;          // 0..15, rows row0 .. row0+3
    const long row0 = (long)blockIdx.x * 64 + (long)ty * 4;

    // clamped row base pointers (tail rows read row Ni-1; store is guarded)
    const float* xr[4];
    #pragma unroll
    for (int r = 0; r < 4; ++r) {
        long rr = row0 + r;
        if (rr > (long)Ni - 1) rr = (long)Ni - 1;
        xr[r] = x + rr * D;
    }
    const float* wp = W + tx * 8;

    float acc[4][8] = {};
    float4 wA[8], wB[8], xA[4], xB[4];

    // preload set A = k 0..3
    #pragma unroll
    for (int kk = 0; kk < 4; ++kk) {
        wA[2 * kk]     = *(const float4*)&wp[kk * D];
        wA[2 * kk + 1] = *(const float4*)&wp[kk * D + 4];
    }
    #pragma unroll
    for (int r = 0; r < 4; ++r) xA[r] = *(const float4*)&xr[r][0];

    #pragma unroll 1
    for (int k = 0; k < D; k += 8) {
        // issue set B loads (k+4 .. k+7)
        #pragma unroll
        for (int kk = 0; kk < 4; ++kk) {
            wB[2 * kk]     = *(const float4*)&wp[(k + 4 + kk) * D];
            wB[2 * kk + 1] = *(const float4*)&wp[(k + 4 + kk) * D + 4];
        }
        #pragma unroll
        for (int r = 0; r < 4; ++r) xB[r] = *(const float4*)&xr[r][k + 4];

        // FMA on set A (k .. k+3)
        #pragma unroll
        for (int r = 0; r < 4; ++r) {
            #pragma unroll
            for (int kk = 0; kk < 4; ++kk) {
                const float xk = (kk == 0) ? xA[r].x : (kk == 1) ? xA[r].y
                               : (kk == 2) ? xA[r].z : xA[r].w;
                acc[r][0] += xk * wA[2 * kk].x;
                acc[r][1] += xk * wA[2 * kk].y;
                acc[r][2] += xk * wA[2 * kk].z;
                acc[r][3] += xk * wA[2 * kk].w;
                acc[r][4] += xk * wA[2 * kk + 1].x;
                acc[r][5] += xk * wA[2 * kk + 1].y;
                acc[r][6] += xk * wA[2 * kk + 1].z;
                acc[r][7] += xk * wA[2 * kk + 1].w;
            }
        }

        // issue next set A loads (k+8 .. k+11), guarded (uniform branch)
        if (k + 8 < D) {
            #pragma unroll
            for (int kk = 0; kk < 4; ++kk) {
                wA[2 * kk]     = *(const float4*)&wp[(k + 8 + kk) * D];
                wA[2 * kk + 1] = *(const float4*)&wp[(k + 8 + kk) * D + 4];
            }
            #pragma unroll
            for (int r = 0; r < 4; ++r) xA[r] = *(const float4*)&xr[r][k + 8];
        }

        // FMA on set B (k+4 .. k+7)
        #pragma unroll
        for (int r = 0; r < 4; ++r) {
            #pragma unroll
            for (int kk = 0; kk < 4; ++kk) {
                const float xk = (kk == 0) ? xB[r].x : (kk == 1) ? xB[r].y
                               : (kk == 2) ? xB[r].z : xB[r].w;
                acc[r][0] += xk * wB[2 * kk].x;
                acc[r][1] += xk * wB[2 * kk].y;
                acc[r][2] += xk * wB[2 * kk].z;
                acc[r][3] += xk * wB[2 * kk].w;
                acc[r][4] += xk * wB[2 * kk + 1].x;
                acc[r][5] += xk * wB[2 * kk + 1].y;
                acc[r][6] += xk * wB[2 * kk + 1].z;
                acc[r][7] += xk * wB[2 * kk + 1].w;
            }
        }
    }

    const float4 bb0 = *(const float4*)&b[tx * 8];
    const float4 bb1 = *(const float4*)&b[tx * 8 + 4];
    const float4 aa0 = *(const float4*)&att[tx * 8];
    const float4 aa1 = *(const float4*)&att[tx * 8 + 4];
    #pragma unroll
    for (int r = 0; r < 4; ++r) {
        long row = row0 + r;
        if (row < Ni) {
            float4 h0, h1;
            h0.x = acc[r][0] + bb0.x;  h0.y = acc[r][1] + bb0.y;
            h0.z = acc[r][2] + bb0.z;  h0.w = acc[r][3] + bb0.w;
            h1.x = acc[r][4] + bb1.x;  h1.y = acc[r][5] + bb1.y;
            h1.z = acc[r][6] + bb1.z;  h1.w = acc[r][7] + bb1.w;
            *(float4*)&h[row * D + tx * 8]     = h0;
            *(float4*)&h[row * D + tx * 8 + 4] = h1;
            float p = h0.x * aa0.x + h0.y * aa0.y + h0.z * aa0.z + h0.w * aa0.w
                    + h1.x * aa1.x + h1.y * aa1.y + h1.z * aa1.z + h1.w * aa1.w;
            p += __shfl_xor(p, 1, 64);
            p += __shfl_xor(p, 2, 64);
            p += __shfl_xor(p, 4, 64);
            p += __shfl_xor(p, 8, 64);
            if (tx == 0) a_src[row] = p;
        }
    }
}

// ---------------------------------------------------------------------------
// Counting sort: histogram -> 1-block scan -> scatter (packs src + a_src[src]
// into one int2 so the random write is a single 8B store)
// ---------------------------------------------------------------------------
__global__ void k_hist(const int* __restrict__ dst, int* __restrict__ hist, int E) {
    int i = blockIdx.x * 256 + threadIdx.x;
    if (i < E) atomicAdd(&hist[dst[i]], 1);
}

__global__ __launch_bounds__(1024)
void k_scan(const int* __restrict__ hist, int* __restrict__ offs,
            int* __restrict__ cur, int n) {
    __shared__ int sh[1024];
    int tid = threadIdx.x;
    int chunk = (n + 1023) / 1024;
    int start = tid * chunk;
    int end   = min(start + chunk, n);
    int sum = 0;
    for (int i = start; i < end; ++i) sum += hist[i];
    sh[tid] = sum;
    __syncthreads();
    for (int o = 1; o < 1024; o <<= 1) {
        int v = (tid >= o) ? sh[tid - o] : 0;
        __syncthreads();
        sh[tid] += v;
        __syncthreads();
    }
    int run = sh[tid] - sum;  // exclusive prefix
    for (int i = start; i < end; ++i) {
        offs[i] = run; cur[i] = run; run += hist[i];
    }
    if (tid == 1023) offs[n] = run;
}

__global__ void k_scatter(const int* __restrict__ src, const int* __restrict__ dst,
                          const float* __restrict__ a_src, int* __restrict__ cur,
                          int2* __restrict__ s_pack, int E) {
    int i = blockIdx.x * 256 + threadIdx.x;
    if (i >= E) return;
    int d = dst[i], s = src[i];
    int pos = atomicAdd(&cur[d], 1);
    s_pack[pos] = make_int2(s, __float_as_int(a_src[s]));
}

// ---------------------------------------------------------------------------
// K_agg: one wave per taste node. a_dst is computed INLINE (x_taste row is
// needed for the residual anyway; the former k_adst kernel and its 25.6 MB
// pass are deleted). Edge metadata preloaded lane-parallel, exp() per lane,
// gather loop broadcasts (s,w) via shfl with 4-way unroll / split
// accumulators for memory-level parallelism. 1/z applied once at the end
// (softmax max-subtract unnecessary: |alpha| <~ 10).
// ---------------------------------------------------------------------------
__global__ __launch_bounds__(256)
void k_agg(const int* __restrict__ offs, const int2* __restrict__ s_pack,
           const float* __restrict__ v_c, const float* __restrict__ h,
           const float* __restrict__ xt, float* __restrict__ outT, int Nt) {
    int t    = blockIdx.x * 4 + (threadIdx.x >> 6);
    int lane = threadIdx.x & 63;
    if (t >= Nt) return;

    // residual read + inline a_dst = x_taste[t].v + c
    float2 xv = *(const float2*)&xt[(long)t * D + lane * 2];
    float2 vv = *(const float2*)&v_c[lane * 2];
    float ad  = reduce_add_wave64(xv.x * vv.x + xv.y * vv.y) + v_c[D];

    int s0 = offs[t], s1 = offs[t + 1];
    int deg = s1 - s0;

    // lane-parallel preload of first 64 edges
    int   my_s = 0;
    float my_e = 0.f;
    if (lane < deg) {
        int2 sp = s_pack[s0 + lane];
        my_s = sp.x;
        float al = __int_as_float(sp.y) + ad;
        al = al > 0.f ? al : 0.2f * al;
        my_e = __expf(al);
    }
    float z = my_e;
    for (int i = s0 + 64 + lane; i < s1; i += 64) {   // rare (deg > 64)
        int2 sp = s_pack[i];
        float al = __int_as_float(sp.y) + ad;
        al = al > 0.f ? al : 0.2f * al;
        z += __expf(al);
    }
    z = reduce_add_wave64(z);
    float zinv = 1.0f / (z + 1e-16f);

    float2 acc0 = {0.f, 0.f}, acc1 = {0.f, 0.f};
    float2 acc2 = {0.f, 0.f}, acc3 = {0.f, 0.f};
    int n = deg < 64 ? deg : 64;
    int i = 0;
    for (; i + 3 < n; i += 4) {
        int   sA = __shfl(my_s, i, 64);     float wA = __shfl(my_e, i, 64);
        int   sB = __shfl(my_s, i + 1, 64); float wB = __shfl(my_e, i + 1, 64);
        int   sC = __shfl(my_s, i + 2, 64); float wC = __shfl(my_e, i + 2, 64);
        int   sD = __shfl(my_s, i + 3, 64); float wD = __shfl(my_e, i + 3, 64);
        float2 hA = *(const float2*)&h[(long)sA * D + lane * 2];
        float2 hB = *(const float2*)&h[(long)sB * D + lane * 2];
        float2 hC = *(const float2*)&h[(long)sC * D + lane * 2];
        float2 hD = *(const float2*)&h[(long)sD * D + lane * 2];
        acc0.x += hA.x * wA;  acc0.y += hA.y * wA;
        acc1.x += hB.x * wB;  acc1.y += hB.y * wB;
        acc2.x += hC.x * wC;  acc2.y += hC.y * wC;
        acc3.x += hD.x * wD;  acc3.y += hD.y * wD;
    }
    for (; i < n; ++i) {
        int   sA = __shfl(my_s, i, 64);
        float wA = __shfl(my_e, i, 64);
        float2 hA = *(const float2*)&h[(long)sA * D + lane * 2];
        acc0.x += hA.x * wA;  acc0.y += hA.y * wA;
    }
    for (int j = s0 + 64; j < s1; ++j) {              // rare (deg > 64)
        int2 sp = s_pack[j];
        float al = __int_as_float(sp.y) + ad;
        al = al > 0.f ? al : 0.2f * al;
        float w = __expf(al);
        float2 hv = *(const float2*)&h[(long)sp.x * D + lane * 2];
        acc0.x += hv.x * w;  acc0.y += hv.y * w;
    }

    float2 o;
    o.x = fmaxf((acc0.x + acc1.x + acc2.x + acc3.x) * zinv, 0.f) + xv.x;
    o.y = fmaxf((acc0.y + acc1.y + acc2.y + acc3.y) * zinv, 0.f) + xv.y;
    *(float2*)&outT[(long)t * D + lane * 2] = o;
}

// ---------------------------------------------------------------------------
// K_copy: x_ing -> d_out ingredient region (grid-stride float4)
// ---------------------------------------------------------------------------
__global__ __launch_bounds__(256)
void k_copy(const float4* __restrict__ src, float4* __restrict__ dst, long n4) {
    long stride = (long)gridDim.x * 256;
    for (long i = (long)blockIdx.x * 256 + threadIdx.x; i < n4; i += stride)
        dst[i] = src[i];
}

// ---------------------------------------------------------------------------
// BatchNorm: column sums/sumsq (grid-partial + atomics), then normalize+ReLU
// ---------------------------------------------------------------------------
__global__ __launch_bounds__(256)
void k_bnstats(const float* __restrict__ outT, float* __restrict__ csum,
               float* __restrict__ csq, int Nt) {
    int c    = threadIdx.x & 127;
    int half = threadIdx.x >> 7;
    float s = 0.f, q = 0.f;
    for (int r = blockIdx.x * 2 + half; r < Nt; r += gridDim.x * 2) {
        float v = outT[(long)r * D + c];
        s += v; q += v * v;
    }
    atomicAdd(&csum[c], s);
    atomicAdd(&csq[c], q);
}

__global__ __launch_bounds__(256)
void k_bnapply(float* __restrict__ outT, const float* __restrict__ csum,
               const float* __restrict__ csq, const float* __restrict__ gamma,
               const float* __restrict__ beta, int Nt) {
    int i4 = blockIdx.x * 256 + threadIdx.x;
    int total = Nt * (D / 4);
    if (i4 >= total) return;
    int c = (i4 * 4) & 127;
    float invN = 1.0f / (float)Nt;
    float4 v = *(float4*)&outT[(long)i4 * 4];
    float4 o;
    {
        float m0 = csum[c + 0] * invN, m1 = csum[c + 1] * invN;
        float m2 = csum[c + 2] * invN, m3 = csum[c + 3] * invN;
        float r0 = rsqrtf(csq[c + 0] * invN - m0 * m0 + 1e-5f);
        float r1 = rsqrtf(csq[c + 1] * invN - m1 * m1 + 1e-5f);
        float r2 = rsqrtf(csq[c + 2] * invN - m2 * m2 + 1e-5f);
        float r3 = rsqrtf(csq[c + 3] * invN - m3 * m3 + 1e-5f);
        o.x = fmaxf(gamma[c + 0] * (v.x - m0) * r0 + beta[c + 0], 0.f);
        o.y = fmaxf(gamma[c + 1] * (v.y - m1) * r1 + beta[c + 1], 0.f);
        o.z = fmaxf(gamma[c + 2] * (v.z - m2) * r2 + beta[c + 2], 0.f);
        o.w = fmaxf(gamma[c + 3] * (v.w - m3) * r3 + beta[c + 3], 0.f);
    }
    *(float4*)&outT[(long)i4 * 4] = o;
}

// ---------------------------------------------------------------------------
extern "C" void kernel_launch(void* const* d_in, const int* in_sizes, int n_in,
                              void* d_out, int out_size, void* d_ws, size_t ws_size,
                              hipStream_t stream) {
    const float* x_ing   = (const float*)d_in[0];
    const float* x_taste = (const float*)d_in[1];
    const float* W_ing   = (const float*)d_in[2];
    const float* b_ing   = (const float*)d_in[3];
    const float* W_taste = (const float*)d_in[4];
    const float* b_taste = (const float*)d_in[5];
    const float* att_src = (const float*)d_in[6];
    const float* att_dst = (const float*)d_in[7];
    const float* gamma   = (const float*)d_in[8];
    const float* beta    = (const float*)d_in[9];
    const int*   e_src   = (const int*)d_in[10];
    const int*   e_dst   = (const int*)d_in[11];

    const int Ni = in_sizes[0] / D;
    const int Nt = in_sizes[1] / D;
    const int E  = in_sizes[10];

    // h lives in d_out's ingredient region (exactly Ni*D floats); the
    // x_ing passthrough copy happens AFTER k_agg has consumed h.
    float* h    = (float*)d_out;
    float* outT = (float*)d_out + (size_t)Ni * D;

    // workspace carve (each region rounded to 64 floats = 256B); ~7 MB total
    float* ws = (float*)d_ws;
    size_t off = 0;
    auto alloc = [&](size_t n) {
        float* p = ws + off;
        off += (n + 63) & ~(size_t)63;
        return p;
    };
    float* asrc   = alloc(Ni);
    float* v_c    = alloc(D + 64);
    int*   hist   = (int*)alloc(Nt);         // zeroed (contiguous with csum/csq)
    float* csum   = alloc(D);                // zeroed
    float* csq    = alloc(D);                // zeroed
    int*   offs   = (int*)alloc(Nt + 1);
    int*   cur    = (int*)alloc(Nt);
    int2*  s_pack = (int2*)alloc((size_t)E * 2);
    (void)off; (void)ws_size; (void)n_in; (void)out_size;

    // zero hist + csum + csq in one shot (contiguous in ws)
    size_t histR = ((size_t)Nt + 63) & ~(size_t)63;
    hipMemsetAsync(hist, 0, (histR + 256) * sizeof(float), stream);

    k_prep<<<1, 128, 0, stream>>>(W_taste, b_taste, att_dst, v_c);
    k_gemm_hi<<<(Ni + 63) / 64, 256, 0, stream>>>(x_ing, W_ing, b_ing,
                                                  att_src, h, asrc, Ni);
    k_hist<<<(E + 255) / 256, 256, 0, stream>>>(e_dst, hist, E);
    k_scan<<<1, 1024, 0, stream>>>(hist, offs, cur, Nt);
    k_scatter<<<(E + 255) / 256, 256, 0, stream>>>(e_src, e_dst, asrc, cur,
                                                   s_pack, E);
    k_agg<<<(Nt + 3) / 4, 256, 0, stream>>>(offs, s_pack, v_c, h,
                                            x_taste, outT, Nt);

    // ingredient output = input passthrough (after h is consumed)
    long n4 = (long)Ni * D / 4;
    k_copy<<<2048, 256, 0, stream>>>((const float4*)x_ing, (float4*)d_out, n4);

    k_bnstats<<<512, 256, 0, stream>>>(outT, csum, csq, Nt);
    k_bnapply<<<(Nt * (D / 4) + 255) / 256, 256, 0, stream>>>(outT, csum, csq,
                                                              gamma, beta, Nt);
}

// Round 7
// 358.695 us; speedup vs baseline: 1.5156x; 1.4135x over previous
//
#include <hip/hip_runtime.h>
#include <math.h>

#define D 128

__device__ __forceinline__ float reduce_add_wave64(float v) {
    #pragma unroll
    for (int m = 32; m >= 1; m >>= 1) v += __shfl_xor(v, m, 64);
    return v;
}
__device__ __forceinline__ int reduce_add_wave64_i(int v) {
    #pragma unroll
    for (int m = 32; m >= 1; m >>= 1) v += __shfl_xor(v, m, 64);
    return v;
}

// ---------------------------------------------------------------------------
// K_prep: v = W_taste @ att_dst ; c = b_taste.att_dst   (one wave per output)
// ---------------------------------------------------------------------------
__global__ __launch_bounds__(256)
void k_prep(const float* __restrict__ Wt, const float* __restrict__ bt,
            const float* __restrict__ attd, float* __restrict__ v_c) {
    int w    = (blockIdx.x * 256 + threadIdx.x) >> 6;
    int lane = threadIdx.x & 63;
    if (w > D) return;
    float2 a = *(const float2*)&attd[lane * 2];
    const float* rowp = (w < D) ? &Wt[(long)w * D] : bt;
    float2 rv = *(const float2*)&rowp[lane * 2];
    float p = reduce_add_wave64(rv.x * a.x + rv.y * a.y);
    if (lane == 0) v_c[w] = p;   // w==D writes c into v_c[D]
}

// ---------------------------------------------------------------------------
// K_gemm: h = x_ing @ W_ing + b_ing  [Ni,128]; a_src = h @ att_src  [Ni]
// W staged in LDS (64KB only -> 2 blocks/CU, 8 waves/CU; r2's failure was
// 128KB -> 1 block/CU; r5/r6's failure was global-W L2 latency). Columns
// split as tx*4 and 64+tx*4 so each ds_read_b128 covers a contiguous 256B
// half-row: 2 lanes/bank = conflict-free (m136). x rows are 16-lane global
// broadcasts, double-buffered one 4-k phase ahead.
// ---------------------------------------------------------------------------
__global__ __launch_bounds__(256, 2)
void k_gemm_hi(const float* __restrict__ x, const float* __restrict__ W,
               const float* __restrict__ b, const float* __restrict__ att,
               float* __restrict__ h, float* __restrict__ a_src, int Ni) {
    __shared__ float sW[D * D];   // 64 KB
    const int tid = threadIdx.x;
    #pragma unroll
    for (int j = 0; j < 16; ++j) {
        int idx = (j * 256 + tid) * 4;
        *(float4*)&sW[idx] = *(const float4*)&W[idx];
    }

    const int tx = tid & 15;            // col groups tx*4 and 64+tx*4
    const int ty = tid >> 4;            // 0..15, rows row0..row0+3
    const long row0 = (long)blockIdx.x * 64 + (long)ty * 4;
    const int c0 = tx * 4, c1 = 64 + tx * 4;

    const float* xr[4];
    #pragma unroll
    for (int r = 0; r < 4; ++r) {
        long rr = row0 + r;
        if (rr > (long)Ni - 1) rr = (long)Ni - 1;
        xr[r] = x + rr * D;
    }

    float4 xa[4], xb[4];
    #pragma unroll
    for (int r = 0; r < 4; ++r) xa[r] = *(const float4*)&xr[r][0];
    #pragma unroll
    for (int r = 0; r < 4; ++r) xb[r] = *(const float4*)&xr[r][4];

    __syncthreads();

    float acc[4][8] = {};

    #pragma unroll 1
    for (int k = 0; k < D; k += 8) {
        // phase A: rows k..k+3 from xa
        #pragma unroll
        for (int kk = 0; kk < 4; ++kk) {
            const float4 w0 = *(const float4*)&sW[(k + kk) * D + c0];
            const float4 w1 = *(const float4*)&sW[(k + kk) * D + c1];
            #pragma unroll
            for (int r = 0; r < 4; ++r) {
                const float xk = (kk == 0) ? xa[r].x : (kk == 1) ? xa[r].y
                               : (kk == 2) ? xa[r].z : xa[r].w;
                acc[r][0] += xk * w0.x;  acc[r][1] += xk * w0.y;
                acc[r][2] += xk * w0.z;  acc[r][3] += xk * w0.w;
                acc[r][4] += xk * w1.x;  acc[r][5] += xk * w1.y;
                acc[r][6] += xk * w1.z;  acc[r][7] += xk * w1.w;
            }
        }
        if (k + 8 < D) {   // refill xa for k+8 (consumed above)
            #pragma unroll
            for (int r = 0; r < 4; ++r) xa[r] = *(const float4*)&xr[r][k + 8];
        }
        // phase B: rows k+4..k+7 from xb
        #pragma unroll
        for (int kk = 0; kk < 4; ++kk) {
            const float4 w0 = *(const float4*)&sW[(k + 4 + kk) * D + c0];
            const float4 w1 = *(const float4*)&sW[(k + 4 + kk) * D + c1];
            #pragma unroll
            for (int r = 0; r < 4; ++r) {
                const float xk = (kk == 0) ? xb[r].x : (kk == 1) ? xb[r].y
                               : (kk == 2) ? xb[r].z : xb[r].w;
                acc[r][0] += xk * w0.x;  acc[r][1] += xk * w0.y;
                acc[r][2] += xk * w0.z;  acc[r][3] += xk * w0.w;
                acc[r][4] += xk * w1.x;  acc[r][5] += xk * w1.y;
                acc[r][6] += xk * w1.z;  acc[r][7] += xk * w1.w;
            }
        }
        if (k + 12 < D) {  // refill xb for k+12
            #pragma unroll
            for (int r = 0; r < 4; ++r) xb[r] = *(const float4*)&xr[r][k + 12];
        }
    }

    const float4 bb0 = *(const float4*)&b[c0];
    const float4 bb1 = *(const float4*)&b[c1];
    const float4 aa0 = *(const float4*)&att[c0];
    const float4 aa1 = *(const float4*)&att[c1];
    #pragma unroll
    for (int r = 0; r < 4; ++r) {
        long row = row0 + r;
        if (row < Ni) {
            float4 h0, h1;
            h0.x = acc[r][0] + bb0.x;  h0.y = acc[r][1] + bb0.y;
            h0.z = acc[r][2] + bb0.z;  h0.w = acc[r][3] + bb0.w;
            h1.x = acc[r][4] + bb1.x;  h1.y = acc[r][5] + bb1.y;
            h1.z = acc[r][6] + bb1.z;  h1.w = acc[r][7] + bb1.w;
            *(float4*)&h[row * D + c0] = h0;
            *(float4*)&h[row * D + c1] = h1;
            float p = h0.x * aa0.x + h0.y * aa0.y + h0.z * aa0.z + h0.w * aa0.w
                    + h1.x * aa1.x + h1.y * aa1.y + h1.z * aa1.z + h1.w * aa1.w;
            p += __shfl_xor(p, 1, 64);
            p += __shfl_xor(p, 2, 64);
            p += __shfl_xor(p, 4, 64);
            p += __shfl_xor(p, 8, 64);
            if (tx == 0) a_src[row] = p;
        }
    }
}

// ---------------------------------------------------------------------------
// CSR build: histogram -> 3-phase parallel scan -> scatter (packed int2)
// ---------------------------------------------------------------------------
__global__ void k_hist(const int* __restrict__ dst, int* __restrict__ hist, int E) {
    int i = blockIdx.x * 256 + threadIdx.x;
    if (i < E) atomicAdd(&hist[dst[i]], 1);
}

// phase 1: per-block (1024 entries) sums
__global__ __launch_bounds__(256)
void k_scan_part(const int* __restrict__ hist, int* __restrict__ part, int n) {
    __shared__ int sh[4];
    int base = blockIdx.x * 1024 + threadIdx.x * 4;
    int s = 0;
    #pragma unroll
    for (int j = 0; j < 4; ++j) {
        int i = base + j;
        if (i < n) s += hist[i];
    }
    s = reduce_add_wave64_i(s);
    int w = threadIdx.x >> 6;
    if ((threadIdx.x & 63) == 0) sh[w] = s;
    __syncthreads();
    if (threadIdx.x == 0) part[blockIdx.x] = sh[0] + sh[1] + sh[2] + sh[3];
}

// phase 2: exclusive scan of <=64 block sums (one wave); writes offs[n]=total
__global__ __launch_bounds__(64)
void k_scan_top(const int* __restrict__ part, int* __restrict__ top,
                int* __restrict__ offs, int nb, int n) {
    int lane = threadIdx.x;
    int v = (lane < nb) ? part[lane] : 0;
    int incl = v;
    #pragma unroll
    for (int o = 1; o < 64; o <<= 1) {
        int t = __shfl_up(incl, o, 64);
        if (lane >= o) incl += t;
    }
    if (lane < nb) top[lane] = incl - v;
    if (lane == nb - 1) offs[n] = incl;
}

// phase 3: block-local exclusive scan + block offset -> offs, cur
__global__ __launch_bounds__(256)
void k_scan_low(const int* __restrict__ hist, const int* __restrict__ top,
                int* __restrict__ offs, int* __restrict__ cur, int n) {
    __shared__ int sh[4];
    int tid  = threadIdx.x;
    int base = blockIdx.x * 1024 + tid * 4;
    int v[4]; int ts = 0;
    #pragma unroll
    for (int j = 0; j < 4; ++j) {
        int i = base + j;
        v[j] = (i < n) ? hist[i] : 0;
        ts += v[j];
    }
    int lane = tid & 63, w = tid >> 6;
    int incl = ts;
    #pragma unroll
    for (int o = 1; o < 64; o <<= 1) {
        int t = __shfl_up(incl, o, 64);
        if (lane >= o) incl += t;
    }
    if (lane == 63) sh[w] = incl;
    __syncthreads();
    int wbase = 0;
    #pragma unroll
    for (int j = 0; j < 4; ++j) wbase += (j < w) ? sh[j] : 0;
    int run = top[blockIdx.x] + wbase + (incl - ts);
    #pragma unroll
    for (int j = 0; j < 4; ++j) {
        int i = base + j;
        if (i < n) { offs[i] = run; cur[i] = run; }
        run += v[j];
    }
}

__global__ void k_scatter(const int* __restrict__ src, const int* __restrict__ dst,
                          const float* __restrict__ a_src, int* __restrict__ cur,
                          int2* __restrict__ s_pack, int E) {
    int i = blockIdx.x * 256 + threadIdx.x;
    if (i >= E) return;
    int d = dst[i], s = src[i];
    int pos = atomicAdd(&cur[d], 1);
    s_pack[pos] = make_int2(s, __float_as_int(a_src[s]));
}

// ---------------------------------------------------------------------------
// K_agg: one wave per taste node; a_dst inline; lane-parallel edge preload;
// gather loop broadcasts (s,w) via shfl, 4-way unrolled split accumulators.
// ---------------------------------------------------------------------------
__global__ __launch_bounds__(256)
void k_agg(const int* __restrict__ offs, const int2* __restrict__ s_pack,
           const float* __restrict__ v_c, const float* __restrict__ h,
           const float* __restrict__ xt, float* __restrict__ outT, int Nt) {
    int t    = blockIdx.x * 4 + (threadIdx.x >> 6);
    int lane = threadIdx.x & 63;
    if (t >= Nt) return;

    float2 xv = *(const float2*)&xt[(long)t * D + lane * 2];
    float2 vv = *(const float2*)&v_c[lane * 2];
    float ad  = reduce_add_wave64(xv.x * vv.x + xv.y * vv.y) + v_c[D];

    int s0 = offs[t], s1 = offs[t + 1];
    int deg = s1 - s0;

    int   my_s = 0;
    float my_e = 0.f;
    if (lane < deg) {
        int2 sp = s_pack[s0 + lane];
        my_s = sp.x;
        float al = __int_as_float(sp.y) + ad;
        al = al > 0.f ? al : 0.2f * al;
        my_e = __expf(al);
    }
    float z = my_e;
    for (int i = s0 + 64 + lane; i < s1; i += 64) {
        int2 sp = s_pack[i];
        float al = __int_as_float(sp.y) + ad;
        al = al > 0.f ? al : 0.2f * al;
        z += __expf(al);
    }
    z = reduce_add_wave64(z);
    float zinv = 1.0f / (z + 1e-16f);

    float2 acc0 = {0.f, 0.f}, acc1 = {0.f, 0.f};
    float2 acc2 = {0.f, 0.f}, acc3 = {0.f, 0.f};
    int n = deg < 64 ? deg : 64;
    int i = 0;
    for (; i + 3 < n; i += 4) {
        int   sA = __shfl(my_s, i, 64);     float wA = __shfl(my_e, i, 64);
        int   sB = __shfl(my_s, i + 1, 64); float wB = __shfl(my_e, i + 1, 64);
        int   sC = __shfl(my_s, i + 2, 64); float wC = __shfl(my_e, i + 2, 64);
        int   sD = __shfl(my_s, i + 3, 64); float wD = __shfl(my_e, i + 3, 64);
        float2 hA = *(const float2*)&h[(long)sA * D + lane * 2];
        float2 hB = *(const float2*)&h[(long)sB * D + lane * 2];
        float2 hC = *(const float2*)&h[(long)sC * D + lane * 2];
        float2 hD = *(const float2*)&h[(long)sD * D + lane * 2];
        acc0.x += hA.x * wA;  acc0.y += hA.y * wA;
        acc1.x += hB.x * wB;  acc1.y += hB.y * wB;
        acc2.x += hC.x * wC;  acc2.y += hC.y * wC;
        acc3.x += hD.x * wD;  acc3.y += hD.y * wD;
    }
    for (; i < n; ++i) {
        int   sA = __shfl(my_s, i, 64);
        float wA = __shfl(my_e, i, 64);
        float2 hA = *(const float2*)&h[(long)sA * D + lane * 2];
        acc0.x += hA.x * wA;  acc0.y += hA.y * wA;
    }
    for (int j = s0 + 64; j < s1; ++j) {
        int2 sp = s_pack[j];
        float al = __int_as_float(sp.y) + ad;
        al = al > 0.f ? al : 0.2f * al;
        float w = __expf(al);
        float2 hv = *(const float2*)&h[(long)sp.x * D + lane * 2];
        acc0.x += hv.x * w;  acc0.y += hv.y * w;
    }

    float2 o;
    o.x = fmaxf((acc0.x + acc1.x + acc2.x + acc3.x) * zinv, 0.f) + xv.x;
    o.y = fmaxf((acc0.y + acc1.y + acc2.y + acc3.y) * zinv, 0.f) + xv.y;
    *(float2*)&outT[(long)t * D + lane * 2] = o;
}

// ---------------------------------------------------------------------------
__global__ __launch_bounds__(256)
void k_copy(const float4* __restrict__ src, float4* __restrict__ dst, long n4) {
    long stride = (long)gridDim.x * 256;
    for (long i = (long)blockIdx.x * 256 + threadIdx.x; i < n4; i += stride)
        dst[i] = src[i];
}

// ---------------------------------------------------------------------------
// BatchNorm: column sums/sumsq (grid-partial + atomics), then normalize+ReLU
// ---------------------------------------------------------------------------
__global__ __launch_bounds__(256)
void k_bnstats(const float* __restrict__ outT, float* __restrict__ csum,
               float* __restrict__ csq, int Nt) {
    int c    = threadIdx.x & 127;
    int half = threadIdx.x >> 7;
    float s = 0.f, q = 0.f;
    for (int r = blockIdx.x * 2 + half; r < Nt; r += gridDim.x * 2) {
        float v = outT[(long)r * D + c];
        s += v; q += v * v;
    }
    atomicAdd(&csum[c], s);
    atomicAdd(&csq[c], q);
}

__global__ __launch_bounds__(256)
void k_bnapply(float* __restrict__ outT, const float* __restrict__ csum,
               const float* __restrict__ csq, const float* __restrict__ gamma,
               const float* __restrict__ beta, int Nt) {
    int i4 = blockIdx.x * 256 + threadIdx.x;
    int total = Nt * (D / 4);
    if (i4 >= total) return;
    int c = (i4 * 4) & 127;
    float invN = 1.0f / (float)Nt;
    float4 v = *(float4*)&outT[(long)i4 * 4];
    float4 o;
    {
        float m0 = csum[c + 0] * invN, m1 = csum[c + 1] * invN;
        float m2 = csum[c + 2] * invN, m3 = csum[c + 3] * invN;
        float r0 = rsqrtf(csq[c + 0] * invN - m0 * m0 + 1e-5f);
        float r1 = rsqrtf(csq[c + 1] * invN - m1 * m1 + 1e-5f);
        float r2 = rsqrtf(csq[c + 2] * invN - m2 * m2 + 1e-5f);
        float r3 = rsqrtf(csq[c + 3] * invN - m3 * m3 + 1e-5f);
        o.x = fmaxf(gamma[c + 0] * (v.x - m0) * r0 + beta[c + 0], 0.f);
        o.y = fmaxf(gamma[c + 1] * (v.y - m1) * r1 + beta[c + 1], 0.f);
        o.z = fmaxf(gamma[c + 2] * (v.z - m2) * r2 + beta[c + 2], 0.f);
        o.w = fmaxf(gamma[c + 3] * (v.w - m3) * r3 + beta[c + 3], 0.f);
    }
    *(float4*)&outT[(long)i4 * 4] = o;
}

// ---------------------------------------------------------------------------
extern "C" void kernel_launch(void* const* d_in, const int* in_sizes, int n_in,
                              void* d_out, int out_size, void* d_ws, size_t ws_size,
                              hipStream_t stream) {
    const float* x_ing   = (const float*)d_in[0];
    const float* x_taste = (const float*)d_in[1];
    const float* W_ing   = (const float*)d_in[2];
    const float* b_ing   = (const float*)d_in[3];
    const float* W_taste = (const float*)d_in[4];
    const float* b_taste = (const float*)d_in[5];
    const float* att_src = (const float*)d_in[6];
    const float* att_dst = (const float*)d_in[7];
    const float* gamma   = (const float*)d_in[8];
    const float* beta    = (const float*)d_in[9];
    const int*   e_src   = (const int*)d_in[10];
    const int*   e_dst   = (const int*)d_in[11];

    const int Ni = in_sizes[0] / D;
    const int Nt = in_sizes[1] / D;
    const int E  = in_sizes[10];
    const int nb = (Nt + 1023) / 1024;   // scan phase-1 blocks (49 for 50000)

    // h lives in d_out's ingredient region (exactly Ni*D floats); the
    // x_ing passthrough copy happens AFTER k_agg has consumed h.
    float* h    = (float*)d_out;
    float* outT = (float*)d_out + (size_t)Ni * D;

    // workspace carve (each region rounded to 64 floats = 256B); ~7 MB total
    float* ws = (float*)d_ws;
    size_t off = 0;
    auto alloc = [&](size_t n) {
        float* p = ws + off;
        off += (n + 63) & ~(size_t)63;
        return p;
    };
    float* asrc   = alloc(Ni);
    float* v_c    = alloc(D + 64);
    int*   hist   = (int*)alloc(Nt);         // zeroed (contiguous with csum/csq)
    float* csum   = alloc(D);                // zeroed
    float* csq    = alloc(D);                // zeroed
    int*   offs   = (int*)alloc(Nt + 1);
    int*   cur    = (int*)alloc(Nt);
    int*   part   = (int*)alloc(64);
    int*   top    = (int*)alloc(64);
    int2*  s_pack = (int2*)alloc((size_t)E * 2);
    (void)off; (void)ws_size; (void)n_in; (void)out_size;

    // zero hist + csum + csq in one shot (contiguous in ws)
    size_t histR = ((size_t)Nt + 63) & ~(size_t)63;
    hipMemsetAsync(hist, 0, (histR + 256) * sizeof(float), stream);

    k_prep<<<(D + 4) / 4, 256, 0, stream>>>(W_taste, b_taste, att_dst, v_c);
    k_gemm_hi<<<(Ni + 63) / 64, 256, 0, stream>>>(x_ing, W_ing, b_ing,
                                                  att_src, h, asrc, Ni);
    k_hist<<<(E + 255) / 256, 256, 0, stream>>>(e_dst, hist, E);
    k_scan_part<<<nb, 256, 0, stream>>>(hist, part, Nt);
    k_scan_top<<<1, 64, 0, stream>>>(part, top, offs, nb, Nt);
    k_scan_low<<<nb, 256, 0, stream>>>(hist, top, offs, cur, Nt);
    k_scatter<<<(E + 255) / 256, 256, 0, stream>>>(e_src, e_dst, asrc, cur,
                                                   s_pack, E);
    k_agg<<<(Nt + 3) / 4, 256, 0, stream>>>(offs, s_pack, v_c, h,
                                            x_taste, outT, Nt);

    // ingredient output = input passthrough (after h is consumed)
    long n4 = (long)Ni * D / 4;
    k_copy<<<2048, 256, 0, stream>>>((const float4*)x_ing, (float4*)d_out, n4);

    k_bnstats<<<512, 256, 0, stream>>>(outT, csum, csq, Nt);
    k_bnapply<<<(Nt * (D / 4) + 255) / 256, 256, 0, stream>>>(outT, csum, csq,
                                                              gamma, beta, Nt);
}